// Round 5
// baseline (161.416 us; speedup 1.0000x reference)
//
#include <hip/hip_runtime.h>
#include <hip/hip_bf16.h>

typedef unsigned short u16;
typedef _Float16 f16;
typedef f16 f16x8 __attribute__((ext_vector_type(8)));
typedef float f32x4 __attribute__((ext_vector_type(4)));

__device__ __forceinline__ float b2f(u16 u) {
  unsigned v = (unsigned)u << 16; float f; __builtin_memcpy(&f, &v, 4); return f;
}
__device__ __forceinline__ u16 f2b(float f) {
  return __builtin_bit_cast(u16, __float2bfloat16(f));
}
__device__ __forceinline__ float h2f(u16 u) {
  return (float)__builtin_bit_cast(f16, u);
}
__device__ __forceinline__ u16 f2h(float f) {
  return __builtin_bit_cast(u16, (f16)f);
}
__device__ __forceinline__ void gload16(const void* g, void* l) {
  __builtin_amdgcn_global_load_lds((__attribute__((address_space(1))) void*)(const_cast<void*>(g)),
                                   (__attribute__((address_space(3))) void*)l, 16, 0, 0);
}
__device__ __forceinline__ f32x4 mfma16(int4 a, int4 b, f32x4 c) {
  return __builtin_amdgcn_mfma_f32_16x16x32_f16(__builtin_bit_cast(f16x8, a),
                                                __builtin_bit_cast(f16x8, b), c, 0, 0, 0);
}
union PK { int4 i; u16 u[8]; };

// ---------------- K-1: dtype detector. f32 buffer: even u16s = mantissa halves, ~44% have exp>=0x90.
__global__ __launch_bounds__(256) void k_detect(const u16* __restrict__ x, int* __restrict__ flag) {
  __shared__ int cnt;
  if (threadIdx.x == 0) cnt = 0;
  __syncthreads();
  int c = 0;
  for (int i = threadIdx.x; i < 4096; i += 256) {
    u16 u = x[i * 2];
    if (((u >> 7) & 0xFF) >= 0x90) ++c;
  }
  atomicAdd(&cnt, c);
  __syncthreads();
  if (threadIdx.x == 0) *flag = (cnt > 64) ? 1 : 0;
}

// ---------------- K0: fused effective 3x3 weights: weff[t=tap*3+br][c][ci] (f16, slot-swizzled) ----
__global__ __launch_bounds__(256) void k_weff(
    const void* __restrict__ w1q, const void* __restrict__ w2q,
    const void* __restrict__ w1k, const void* __restrict__ w2k,
    const void* __restrict__ w1v, const void* __restrict__ w2v,
    const int* __restrict__ flag, u16* __restrict__ weff) {
  __shared__ __align__(16) u16 s1[16384];   // f16 w1[m][ci]
  __shared__ __align__(16) u16 s2[16384];   // f16 w2[c][m] (xor-swizzled)
  int blk = blockIdx.x;                 // tap*3 + br
  int tap = blk / 3, br = blk - tap * 3;
  const void* w1 = br == 0 ? w1q : (br == 1 ? w1k : w1v);
  const void* w2 = br == 0 ? w2q : (br == 1 ? w2k : w2v);
  int tid = threadIdx.x;
  int isf = *flag;
  if (isf) {
    const float* w1f = (const float*)w1;
    for (int i = 0; i < 8; ++i) {
      int e0 = (i * 256 + tid) * 8;
      PK p;
#pragma unroll
      for (int j = 0; j < 8; ++j) p.u[j] = f2h(w1f[e0 + j]);
      ((int4*)s1)[i * 256 + tid] = p.i;
    }
    const float* w2f = (const float*)w2;
    for (int i = 0; i < 64; ++i) {
      int e = i * 256 + tid;            // e = c*128 + m
      int c = e >> 7, m = e & 127;
      s2[c * 128 + (m ^ ((c & 31) << 1))] = f2h(w2f[e * 9 + tap]);
    }
  } else {
    const u16* w1u = (const u16*)w1;
    for (int i = 0; i < 8; ++i) {
      int e0 = (i * 256 + tid) * 8;
      PK p;
#pragma unroll
      for (int j = 0; j < 8; ++j) p.u[j] = f2h(b2f(w1u[e0 + j]));
      ((int4*)s1)[i * 256 + tid] = p.i;
    }
    const u16* w2u = (const u16*)w2;
    for (int i = 0; i < 64; ++i) {
      int e = i * 256 + tid;
      int c = e >> 7, m = e & 127;
      s2[c * 128 + (m ^ ((c & 31) << 1))] = f2h(b2f(w2u[e * 9 + tap]));
    }
  }
  __syncthreads();
  int c = tid & 127, half = tid >> 7;
  for (int g = 0; g < 8; ++g) {
    int ci0 = half * 64 + g * 8;
    float acc[8] = {0, 0, 0, 0, 0, 0, 0, 0};
#pragma unroll 4
    for (int m = 0; m < 128; ++m) {
      float a = h2f(s2[c * 128 + (m ^ ((c & 31) << 1))]);
      PK q; q.i = *(const int4*)((const char*)s1 + m * 256 + ci0 * 2);
#pragma unroll
      for (int j = 0; j < 8; ++j) acc[j] += a * h2f(q.u[j]);
    }
    PK p;
#pragma unroll
    for (int j = 0; j < 8; ++j) p.u[j] = f2h(acc[j]);
    int slot = ci0 >> 3;
    *(int4*)((char*)weff + (size_t)blk * 32768 + c * 256 + ((slot ^ (c & 7)) << 4)) = p.i;
  }
}

// ---------------- K1: LayerNorm over W, write xn_t[b][h][w][c] f16 with slot-swizzle ------------
__global__ __launch_bounds__(128) void k_ln(const void* __restrict__ xr,
    const void* __restrict__ gr, const void* __restrict__ br_,
    const int* __restrict__ flag, u16* __restrict__ xnt) {
  __shared__ __align__(16) u16 sx[16384];   // f16 raw x, [c][slot] slot^=(c&15)
  __shared__ __align__(16) u16 sn[16384];   // f16 xn, [w][c]
  __shared__ float sg[128], sb[128];
  int tid = threadIdx.x;
  int b = blockIdx.x >> 7, h = blockIdx.x & 127;
  int isf = *flag;
  if (isf) { sg[tid] = ((const float*)gr)[tid]; sb[tid] = ((const float*)br_)[tid]; }
  else     { sg[tid] = b2f(((const u16*)gr)[tid]); sb[tid] = b2f(((const u16*)br_)[tid]); }
  __syncthreads();
  int c = tid;
  size_t rowoff = ((size_t)(b * 128 + c) * 128 + (size_t)h) * 128;
  float sum = 0.f, sq = 0.f;
  if (isf) {
    const float* xf = (const float*)xr + rowoff;
#pragma unroll
    for (int i = 0; i < 16; ++i) {
      PK p;
#pragma unroll
      for (int j = 0; j < 8; ++j) {
        float v = xf[i * 8 + j];
        sum += v; sq += v * v;
        p.u[j] = f2h(v);
      }
      *(int4*)((char*)sx + c * 256 + ((i ^ (c & 15)) << 4)) = p.i;
    }
  } else {
    const u16* xu = (const u16*)xr + rowoff;
#pragma unroll
    for (int i = 0; i < 16; ++i) {
      PK p;
#pragma unroll
      for (int j = 0; j < 8; ++j) {
        float v = b2f(xu[i * 8 + j]);
        sum += v; sq += v * v;
        p.u[j] = f2h(v);
      }
      *(int4*)((char*)sx + c * 256 + ((i ^ (c & 15)) << 4)) = p.i;
    }
  }
  float mu = sum * 0.0078125f;
  float var = sq * 0.0078125f - mu * mu;
  float rs = rsqrtf(var + 1e-5f);
#pragma unroll
  for (int i = 0; i < 16; ++i) {
    PK p; p.i = *(const int4*)((const char*)sx + c * 256 + ((i ^ (c & 15)) << 4));
#pragma unroll
    for (int j = 0; j < 8; ++j) {
      int w = i * 8 + j;
      sn[w * 128 + c] = f2h((h2f(p.u[j]) - mu) * rs * sg[w] + sb[w]);
    }
  }
  __syncthreads();
  // coalesced 16B stores: row w, physical slot p holds logical c-slot p^(w&7)
  // 128 rows x 16 slots = 2048 chunks; 128 threads x 16 iters.
  char* obase = (char*)xnt + (size_t)(b * 128 + h) * 32768;
  int p = tid & 15;
#pragma unroll
  for (int i = 0; i < 16; ++i) {
    int wr = i * 8 + (tid >> 4);
    int s = p ^ (wr & 7);
    int4 v = *(const int4*)((const char*)sn + wr * 256 + (s << 4));
    *(int4*)(obase + wr * 256 + (p << 4)) = v;
  }
}

// ---------------- K2: Q,K,V = eff-3x3 conv of xn (MFMA f16), per (b,h) block ----------------------
#define CONV_COMPUTE(ACC) do { \
  _Pragma("unroll") \
  for (int k0i = 0; k0i < 4; ++k0i) { \
    int4 af[4]; \
    _Pragma("unroll") \
    for (int mi = 0; mi < 4; ++mi) { \
      int cc = m0 + mi * 16 + (lane & 15); \
      int slot = (k0i * 4 + (lane >> 4)) ^ (cc & 7); \
      af[mi] = *(const int4*)(wb + cc * 256 + (slot << 4)); \
    } \
    _Pragma("unroll") \
    for (int mi = 0; mi < 4; ++mi) \
      _Pragma("unroll") \
      for (int ni = 0; ni < 4; ++ni) \
        ACC[mi][ni] = mfma16(af[mi], bc[k0i][ni], ACC[mi][ni]); \
  } \
} while (0)

#define EPILOGUE(ACC, OUT) do { \
  _Pragma("unroll") \
  for (int mi = 0; mi < 4; ++mi) \
    _Pragma("unroll") \
    for (int ni = 0; ni < 4; ++ni) { \
      int w = n0 + ni * 16 + (lane & 15); \
      _Pragma("unroll") \
      for (int r = 0; r < 4; ++r) { \
        int cc = m0 + mi * 16 + (lane >> 4) * 4 + r; \
        *(u16*)(wb + cc * 256 + w * 2) = f2h(ACC[mi][ni][r]); \
      } \
    } \
  __syncthreads(); \
  { char* dstp = (char*)(OUT) + (size_t)(b * 128) * 32768 + (size_t)h * 256; \
    _Pragma("unroll") \
    for (int i = 0; i < 8; ++i) { \
      int sl = i * 256 + tid; int cc = sl >> 4; \
      *(int4*)(dstp + (size_t)cc * 32768 + ((sl & 15) << 4)) = *(const int4*)(wb + sl * 16); \
    } } \
  __syncthreads(); \
} while (0)

__global__ __launch_bounds__(256, 1) void k_conv(const u16* __restrict__ xnt,
    const u16* __restrict__ weff, u16* __restrict__ Qc, u16* __restrict__ Kc,
    u16* __restrict__ Vc) {
  __shared__ __align__(16) char smem[131072];   // inb[3][32768] + wb[32768]
  char* inb = smem;
  char* wb = smem + 98304;
  int tid = threadIdx.x, lane = tid & 63, wv = tid >> 6;
  int b = blockIdx.x >> 7, h = blockIdx.x & 127;
  int m0 = (wv >> 1) * 64, n0 = (wv & 1) * 64;

  for (int r = 0; r < 3; ++r) {                 // stage 3 input rows (already swizzled in global)
    int hp = h + r - 1;
    if ((unsigned)hp >= 128u) continue;
    const char* src = (const char*)xnt + (size_t)(b * 128 + hp) * 32768;
    char* dst = inb + r * 32768;
#pragma unroll
    for (int i = 0; i < 8; ++i) {
      int off = i * 4096 + tid * 16;
      gload16(src + off, dst + off);
    }
  }

  f32x4 aq[4][4] = {}, ak[4][4] = {}, av[4][4] = {};
  int4 bc[4][4];

  for (int t = 0; t < 27; ++t) {                // t = tap*3 + branch
    __syncthreads();                            // all reads of prev wb tile done
    {
      const char* wsrc = (const char*)weff + (size_t)t * 32768;
#pragma unroll
      for (int i = 0; i < 8; ++i)
        gload16(wsrc + i * 4096 + tid * 16, wb + i * 4096 + tid * 16);
    }
    __syncthreads();                            // staged (vmcnt drained before barrier)
    int tap = t / 3, br = t - tap * 3;
    int dy = tap / 3, dx = tap - dy * 3;
    int hp = h + dy - 1;
    if ((unsigned)hp >= 128u) continue;         // block-uniform
    const char* bt = inb + dy * 32768;
    if (br == 0) {
#pragma unroll
      for (int k0i = 0; k0i < 4; ++k0i)
#pragma unroll
        for (int ni = 0; ni < 4; ++ni) {
          int wp = n0 + ni * 16 + (lane & 15) + dx - 1;
          bool ok = (unsigned)wp < 128u;
          int wpc = ok ? wp : 0;
          int slot = (k0i * 4 + (lane >> 4)) ^ (wpc & 7);
          int4 v = *(const int4*)(bt + wpc * 256 + (slot << 4));
          if (!ok) v = make_int4(0, 0, 0, 0);
          bc[k0i][ni] = v;
        }
      CONV_COMPUTE(aq);
    } else if (br == 1) {
      CONV_COMPUTE(ak);
    } else {
      CONV_COMPUTE(av);
    }
  }
  __syncthreads();
  EPILOGUE(aq, Qc);
  EPILOGUE(ak, Kc);
  EPILOGUE(av, Vc);
}

// ---------------- K3: Gram attn[b,hd,dk,dq] += sum_v K[v,dk]*Q[v,dq] ------------------------------
__global__ __launch_bounds__(256) void k_gram(const u16* __restrict__ Kc,
    const u16* __restrict__ Qc, float* __restrict__ attnb) {
  __shared__ __align__(16) u16 sk[4096];
  __shared__ __align__(16) u16 sq[4096];
  int tid = threadIdx.x;
  int bi = blockIdx.x;
  int chunk = bi & 63, hd = (bi >> 6) & 7, b = bi >> 9;
  int v0 = chunk * 256;
  int ci = v0 >> 10, h0 = (v0 & 1023) >> 3;
  size_t base = (size_t)(b * 128 + hd * 16 + ci) * 32768 + (size_t)h0 * 256;
  const char* ks = (const char*)Kc + base;
  const char* qs = (const char*)Qc + base;
#pragma unroll
  for (int i = 0; i < 2; ++i) {
    int off = i * 4096 + tid * 16;
    gload16(ks + off, (char*)sk + off);
    gload16(qs + off, (char*)sq + off);
  }
  __syncthreads();
  int dk = tid & 15, dq = tid >> 4;
  float acc = 0.f;
#pragma unroll 8
  for (int v = 0; v < 256; ++v)
    acc += h2f(sk[v * 16 + dk]) * h2f(sq[v * 16 + dq]);
  atomicAdd(&attnb[((b * 8 + hd) * 16 + dk) * 16 + dq], acc);
}

// ---------------- K4: softmax + fold wo: W2[b][co][k=hd*16+dd] (f16, swizzled) --------------------
__global__ __launch_bounds__(256) void k_w2(const float* __restrict__ attnb,
    const void* __restrict__ wo, const void* __restrict__ scale,
    const int* __restrict__ flag, u16* __restrict__ w2s) {
  __shared__ float P[256];
  int b = blockIdx.x, hd = blockIdx.y;
  int tid = threadIdx.x;
  int isf = *flag;
  float sc = isf ? ((const float*)scale)[0] : b2f(((const u16*)scale)[0]);
  float inv_sc = 1.f / sc;
  P[tid] = attnb[(b * 8 + hd) * 256 + tid] * inv_sc;
  __syncthreads();
  if (tid < 16) {
    int dk = tid;
    float m = -1e30f;
#pragma unroll
    for (int j = 0; j < 16; ++j) m = fmaxf(m, P[dk * 16 + j]);
    float e[16]; float s = 0.f;
#pragma unroll
    for (int j = 0; j < 16; ++j) { e[j] = expf(P[dk * 16 + j] - m); s += e[j]; }
    float is = 1.f / s;
#pragma unroll
    for (int j = 0; j < 16; ++j) P[dk * 16 + j] = e[j] * is;
  }
  __syncthreads();
  int co = tid & 127, kg = tid >> 7;
  float wr[16];
  if (isf) {
    const float* wof = (const float*)wo;
#pragma unroll
    for (int d = 0; d < 16; ++d) wr[d] = wof[co * 128 + hd * 16 + d];
  } else {
    const u16* wou = (const u16*)wo;
#pragma unroll
    for (int d = 0; d < 16; ++d) wr[d] = b2f(wou[co * 128 + hd * 16 + d]);
  }
  PK p;
#pragma unroll
  for (int j = 0; j < 8; ++j) {
    int dd = kg * 8 + j;
    float a = 0.f;
#pragma unroll
    for (int d = 0; d < 16; ++d) a += wr[d] * P[dd * 16 + d];
    p.u[j] = f2h(a);
  }
  int slot = hd * 2 + kg;
  *(int4*)((char*)w2s + (size_t)b * 32768 + co * 256 + ((slot ^ (co & 7)) << 4)) = p.i;
}

// ---------------- K5: out = W2 @ Vbrick + x (per (b,h)) -------------------------------------------
__global__ __launch_bounds__(256, 1) void k_final(const u16* __restrict__ w2s,
    const u16* __restrict__ Vc, const void* __restrict__ xr,
    const int* __restrict__ flag, void* __restrict__ outr) {
  __shared__ __align__(16) char sW[32768];
  __shared__ __align__(16) char sBk[32768];
  int tid = threadIdx.x, lane = tid & 63, wv = tid >> 6;
  int b = blockIdx.x >> 7, h = blockIdx.x & 127;
  int isf = *flag;
  const char* wsrc = (const char*)w2s + (size_t)b * 32768;
#pragma unroll
  for (int i = 0; i < 8; ++i) {
    int off = i * 4096 + tid * 16;
    gload16(wsrc + off, sW + off);
  }
#pragma unroll
  for (int i = 0; i < 8; ++i) {                 // V brick: 128 gathered rows of Vc
    int gi = i * 256 + tid;
    int r = gi >> 4;
    int cv = (r >> 4) * 16 + (h >> 3);
    int hv = (h & 7) * 16 + (r & 15);
    const char* src = (const char*)Vc + (size_t)(b * 128 + cv) * 32768 + (size_t)hv * 256 + ((gi & 15) << 4);
    gload16(src, sBk + gi * 16);
  }
  __syncthreads();
  int m0 = (wv >> 1) * 64, n0 = (wv & 1) * 64;
  f32x4 acc[4][4] = {};
#pragma unroll
  for (int k0i = 0; k0i < 4; ++k0i) {
    int4 af[4], bfr[4];
#pragma unroll
    for (int mi = 0; mi < 4; ++mi) {
      int cc = m0 + mi * 16 + (lane & 15);
      int slot = (k0i * 4 + (lane >> 4)) ^ (cc & 7);
      af[mi] = *(const int4*)(sW + cc * 256 + (slot << 4));
    }
#pragma unroll
    for (int ni = 0; ni < 4; ++ni) {
      int w = n0 + ni * 16 + (lane & 15);
      int k = k0i * 32 + (lane >> 4) * 8;
      int hd8 = k >> 4, dd0 = k & 15;
      bfr[ni] = *(const int4*)(sBk + (hd8 * 16 + (w >> 3)) * 256 + ((w & 7) * 32 + dd0 * 2));
    }
#pragma unroll
    for (int mi = 0; mi < 4; ++mi)
#pragma unroll
      for (int ni = 0; ni < 4; ++ni)
        acc[mi][ni] = mfma16(af[mi], bfr[ni], acc[mi][ni]);
  }
  __syncthreads();
  if (isf) {
    const float* xf = (const float*)xr;
    float* of = (float*)outr;
#pragma unroll
    for (int mi = 0; mi < 4; ++mi)
#pragma unroll
      for (int ni = 0; ni < 4; ++ni) {
        int w = n0 + ni * 16 + (lane & 15);
#pragma unroll
        for (int r = 0; r < 4; ++r) {
          int cc = m0 + mi * 16 + (lane >> 4) * 4 + r;
          size_t idx = ((size_t)(b * 128 + cc) * 128 + (size_t)h) * 128 + w;
          of[idx] = acc[mi][ni][r] + xf[idx];
        }
      }
  } else {
    const u16* xu = (const u16*)xr;
#pragma unroll
    for (int mi = 0; mi < 4; ++mi)
#pragma unroll
      for (int ni = 0; ni < 4; ++ni) {
        int w = n0 + ni * 16 + (lane & 15);
#pragma unroll
        for (int r = 0; r < 4; ++r) {
          int cc = m0 + mi * 16 + (lane >> 4) * 4 + r;
          size_t idx = ((size_t)(b * 128 + cc) * 128 + (size_t)h) * 128 + w;
          *(u16*)(sW + cc * 256 + w * 2) = f2b(acc[mi][ni][r] + b2f(xu[idx]));
        }
      }
    __syncthreads();
    char* dstp = (char*)outr + (size_t)(b * 128) * 32768 + (size_t)h * 256;
#pragma unroll
    for (int i = 0; i < 8; ++i) {
      int sl = i * 256 + tid;
      int cc = sl >> 4;
      *(int4*)(dstp + (size_t)cc * 32768 + ((sl & 15) << 4)) = *(const int4*)(sW + sl * 16);
    }
  }
}

extern "C" void kernel_launch(void* const* d_in, const int* in_sizes, int n_in,
                              void* d_out, int out_size, void* d_ws, size_t ws_size,
                              hipStream_t stream) {
  (void)in_sizes; (void)n_in; (void)out_size; (void)ws_size;
  const void* x     = d_in[0];
  const void* gamma = d_in[1];
  const void* beta  = d_in[2];
  const void* scale = d_in[3];
  const void* w1q = d_in[4];
  const void* w2q = d_in[5];
  const void* w1k = d_in[6];
  const void* w2k = d_in[7];
  const void* w1v = d_in[8];
  const void* w2v = d_in[9];
  const void* wo  = d_in[10];
  char* ws = (char*)d_ws;
  u16* xnt     = (u16*)(ws);                           // 8 MB  [b][h][w][c] f16 swizzled
  u16* weff    = (u16*)(ws + (8u << 20));              // 864 KB fused 3x3 weights f16, swizzled
  u16* Qc      = (u16*)(ws + (9u << 20));              // 8 MB each, [b][c][h][w] f16
  u16* Kc      = (u16*)(ws + (17u << 20));
  u16* Vc      = (u16*)(ws + (25u << 20));
  float* attnb = (float*)(ws + (33u << 20));           // 16 KB f32
  u16* w2s     = (u16*)(ws + (33u << 20) + 65536);     // 64 KB f16, swizzled
  int* flag    = (int*)(ws + (33u << 20) + 196608);

  hipMemsetAsync(attnb, 0, 2 * 8 * 16 * 16 * sizeof(float), stream);
  hipLaunchKernelGGL(k_detect, dim3(1), dim3(256), 0, stream, (const u16*)x, flag);
  hipLaunchKernelGGL(k_weff, dim3(27), dim3(256), 0, stream, w1q, w2q, w1k, w2k, w1v, w2v, flag, weff);
  hipLaunchKernelGGL(k_ln, dim3(256), dim3(128), 0, stream, x, gamma, beta, flag, xnt);
  hipLaunchKernelGGL(k_conv, dim3(256), dim3(256), 0, stream, xnt, weff, Qc, Kc, Vc);
  hipLaunchKernelGGL(k_gram, dim3(1024), dim3(256), 0, stream, Kc, Qc, attnb);
  hipLaunchKernelGGL(k_w2, dim3(2, 8), dim3(256), 0, stream, attnb, wo, scale, flag, w2s);
  hipLaunchKernelGGL(k_final, dim3(256), dim3(256), 0, stream, w2s, Vc, x, flag, d_out);
}

// Round 6
// 160.820 us; speedup vs baseline: 1.0037x; 1.0037x over previous
//
#include <hip/hip_runtime.h>
#include <hip/hip_bf16.h>

typedef unsigned short u16;
typedef _Float16 f16;
typedef f16 f16x8 __attribute__((ext_vector_type(8)));
typedef float f32x4 __attribute__((ext_vector_type(4)));

__device__ __forceinline__ float b2f(u16 u) {
  unsigned v = (unsigned)u << 16; float f; __builtin_memcpy(&f, &v, 4); return f;
}
__device__ __forceinline__ u16 f2b(float f) {
  return __builtin_bit_cast(u16, __float2bfloat16(f));
}
__device__ __forceinline__ float h2f(u16 u) {
  return (float)__builtin_bit_cast(f16, u);
}
__device__ __forceinline__ u16 f2h(float f) {
  return __builtin_bit_cast(u16, (f16)f);
}
__device__ __forceinline__ void gload16(const void* g, void* l) {
  __builtin_amdgcn_global_load_lds((__attribute__((address_space(1))) void*)(const_cast<void*>(g)),
                                   (__attribute__((address_space(3))) void*)l, 16, 0, 0);
}
__device__ __forceinline__ f32x4 mfma16(int4 a, int4 b, f32x4 c) {
  return __builtin_amdgcn_mfma_f32_16x16x32_f16(__builtin_bit_cast(f16x8, a),
                                                __builtin_bit_cast(f16x8, b), c, 0, 0, 0);
}
union PK { int4 i; u16 u[8]; };

// ---------------- K-1: dtype detector. f32 buffer: even u16s = mantissa halves, ~44% have exp>=0x90.
__global__ __launch_bounds__(256) void k_detect(const u16* __restrict__ x, int* __restrict__ flag) {
  __shared__ int cnt;
  if (threadIdx.x == 0) cnt = 0;
  __syncthreads();
  int c = 0;
  for (int i = threadIdx.x; i < 4096; i += 256) {
    u16 u = x[i * 2];
    if (((u >> 7) & 0xFF) >= 0x90) ++c;
  }
  atomicAdd(&cnt, c);
  __syncthreads();
  if (threadIdx.x == 0) *flag = (cnt > 64) ? 1 : 0;
}

// ---------------- K0: fused effective 3x3 weights: weff[t=tap*3+br][c][ci] (f16, LINEAR layout) ----
__global__ __launch_bounds__(256) void k_weff(
    const void* __restrict__ w1q, const void* __restrict__ w2q,
    const void* __restrict__ w1k, const void* __restrict__ w2k,
    const void* __restrict__ w1v, const void* __restrict__ w2v,
    const int* __restrict__ flag, u16* __restrict__ weff) {
  __shared__ __align__(16) u16 s1[16384];   // f16 w1[m][ci]
  __shared__ __align__(16) u16 s2[16384];   // f16 w2[c][m] (xor-swizzled)
  int blk = blockIdx.x;                 // tap*3 + br
  int tap = blk / 3, br = blk - tap * 3;
  const void* w1 = br == 0 ? w1q : (br == 1 ? w1k : w1v);
  const void* w2 = br == 0 ? w2q : (br == 1 ? w2k : w2v);
  int tid = threadIdx.x;
  int isf = *flag;
  if (isf) {
    const float* w1f = (const float*)w1;
    for (int i = 0; i < 8; ++i) {
      int e0 = (i * 256 + tid) * 8;
      PK p;
#pragma unroll
      for (int j = 0; j < 8; ++j) p.u[j] = f2h(w1f[e0 + j]);
      ((int4*)s1)[i * 256 + tid] = p.i;
    }
    const float* w2f = (const float*)w2;
    for (int i = 0; i < 64; ++i) {
      int e = i * 256 + tid;            // e = c*128 + m
      int c = e >> 7, m = e & 127;
      s2[c * 128 + (m ^ ((c & 31) << 1))] = f2h(w2f[e * 9 + tap]);
    }
  } else {
    const u16* w1u = (const u16*)w1;
    for (int i = 0; i < 8; ++i) {
      int e0 = (i * 256 + tid) * 8;
      PK p;
#pragma unroll
      for (int j = 0; j < 8; ++j) p.u[j] = f2h(b2f(w1u[e0 + j]));
      ((int4*)s1)[i * 256 + tid] = p.i;
    }
    const u16* w2u = (const u16*)w2;
    for (int i = 0; i < 64; ++i) {
      int e = i * 256 + tid;
      int c = e >> 7, m = e & 127;
      s2[c * 128 + (m ^ ((c & 31) << 1))] = f2h(b2f(w2u[e * 9 + tap]));
    }
  }
  __syncthreads();
  int c = tid & 127, half = tid >> 7;
  for (int g = 0; g < 8; ++g) {
    int ci0 = half * 64 + g * 8;
    float acc[8] = {0, 0, 0, 0, 0, 0, 0, 0};
#pragma unroll 4
    for (int m = 0; m < 128; ++m) {
      float a = h2f(s2[c * 128 + (m ^ ((c & 31) << 1))]);
      PK q; q.i = *(const int4*)((const char*)s1 + m * 256 + ci0 * 2);
#pragma unroll
      for (int j = 0; j < 8; ++j) acc[j] += a * h2f(q.u[j]);
    }
    PK p;
#pragma unroll
    for (int j = 0; j < 8; ++j) p.u[j] = f2h(acc[j]);
    // LINEAR: slot = ci0>>3 (k_conv reads weights straight from global)
    *(int4*)((char*)weff + (size_t)blk * 32768 + c * 256 + ((ci0 >> 3) << 4)) = p.i;
  }
}

// ---------------- K1: LayerNorm over W, write xn_t[b][h][w][c] f16 with slot-swizzle ------------
__global__ __launch_bounds__(256) void k_ln(const void* __restrict__ xr,
    const void* __restrict__ gr, const void* __restrict__ br_,
    const int* __restrict__ flag, u16* __restrict__ xnt) {
  __shared__ __align__(16) float sx[16384];  // 64KB raw f32 x, [c][chunk], phys chunk = logical^(c&31)
  __shared__ __align__(16) u16 sn[16384];    // 32KB f16 xn, [w][c]
  __shared__ float sg[128], sb[128];
  int tid = threadIdx.x;
  int b = blockIdx.x >> 7, h = blockIdx.x & 127;
  int isf = *flag;
  if (tid < 128) {
    sg[tid] = isf ? ((const float*)gr)[tid] : b2f(((const u16*)gr)[tid]);
    sb[tid] = isf ? ((const float*)br_)[tid] : b2f(((const u16*)br_)[tid]);
  }
  if (isf) {
    // coalesced async stage of 128 rows x 512B, source pre-swizzled so LDS dest is linear
#pragma unroll
    for (int it = 0; it < 16; ++it) {
      int d = it * 4096 + tid * 16;     // byte offset in sx
      int c = d >> 9;                   // 512B per row
      int p = (d >> 4) & 31;            // phys 16B chunk
      int sc = p ^ (c & 31);            // source logical chunk
      const char* src = (const char*)xr + (size_t)(b * 128 + c) * 65536 + (size_t)h * 512 + (sc << 4);
      gload16(src, (char*)sx + d);
    }
  } else {
    int c = tid >> 1, half = tid & 1;
    const u16* xu = (const u16*)xr + ((size_t)(b * 128 + c) * 128 + h) * 128 + half * 64;
    for (int i = 0; i < 16; ++i) {
      int phys = (half * 16 + i) ^ (c & 31);
      float* dst = sx + c * 128 + phys * 4;
#pragma unroll
      for (int j = 0; j < 4; ++j) dst[j] = b2f(xu[i * 4 + j]);
    }
  }
  __syncthreads();
  int c = tid >> 1, half = tid & 1;
  float sum = 0.f, sq = 0.f;
#pragma unroll
  for (int i = 0; i < 16; ++i) {
    int phys = (half * 16 + i) ^ (c & 31);
    const float* v = sx + c * 128 + phys * 4;
#pragma unroll
    for (int j = 0; j < 4; ++j) { float f = v[j]; sum += f; sq += f * f; }
  }
  sum += __shfl_xor(sum, 1);
  sq  += __shfl_xor(sq, 1);
  float mu = sum * 0.0078125f;
  float var = sq * 0.0078125f - mu * mu;
  float rs = rsqrtf(var + 1e-5f);
#pragma unroll
  for (int i = 0; i < 16; ++i) {
    int logical = half * 16 + i;
    int phys = logical ^ (c & 31);
    const float* v = sx + c * 128 + phys * 4;
#pragma unroll
    for (int j = 0; j < 4; ++j) {
      int w = logical * 4 + j;
      sn[w * 128 + c] = f2h((v[j] - mu) * rs * sg[w] + sb[w]);
    }
  }
  __syncthreads();
  // coalesced 16B stores: row w, global phys slot p holds logical c-slot p^(w&7)
  char* obase = (char*)xnt + (size_t)(b * 128 + h) * 32768;
#pragma unroll
  for (int i = 0; i < 8; ++i) {
    int sl = i * 256 + tid;
    int wr = sl >> 4, p = sl & 15;
    int s = p ^ (wr & 7);
    *(int4*)(obase + wr * 256 + (p << 4)) = *(const int4*)((const char*)sn + wr * 256 + (s << 4));
  }
}

// ---------------- K2: Q,K,V = eff-3x3 conv of xn (MFMA f16), weights direct from L2 ---------------
#define CONV_COMPUTE2(ACC, WB) do { \
  _Pragma("unroll") \
  for (int k0i = 0; k0i < 4; ++k0i) { \
    int4 af[4]; \
    _Pragma("unroll") \
    for (int mi = 0; mi < 4; ++mi) \
      af[mi] = *(const int4*)((WB) + m0 * 256 + mi * 4096 + k0i * 64 + laneoff); \
    _Pragma("unroll") \
    for (int mi = 0; mi < 4; ++mi) \
      _Pragma("unroll") \
      for (int ni = 0; ni < 4; ++ni) \
        ACC[mi][ni] = mfma16(af[mi], bc[k0i][ni], ACC[mi][ni]); \
  } \
} while (0)

#define EPILOGUE(ACC, OUT) do { \
  _Pragma("unroll") \
  for (int mi = 0; mi < 4; ++mi) \
    _Pragma("unroll") \
    for (int ni = 0; ni < 4; ++ni) { \
      int w = n0 + ni * 16 + (lane & 15); \
      _Pragma("unroll") \
      for (int r = 0; r < 4; ++r) { \
        int cc = m0 + mi * 16 + (lane >> 4) * 4 + r; \
        *(u16*)(scr + cc * 256 + ((((w >> 3) ^ (cc & 7)) << 4) | ((w & 7) << 1))) = f2h(ACC[mi][ni][r]); \
      } \
    } \
  __syncthreads(); \
  { char* dstp = (char*)(OUT) + (size_t)(b * 128) * 32768 + (size_t)h * 256; \
    _Pragma("unroll") \
    for (int i = 0; i < 8; ++i) { \
      int sl = i * 256 + tid; int cc = sl >> 4; int p = sl & 15; \
      int logical = p ^ (cc & 7); \
      *(int4*)(dstp + (size_t)cc * 32768 + (logical << 4)) = *(const int4*)(scr + sl * 16); \
    } } \
  __syncthreads(); \
} while (0)

__global__ __launch_bounds__(256, 1) void k_conv(const u16* __restrict__ xnt,
    const u16* __restrict__ weff, u16* __restrict__ Qc, u16* __restrict__ Kc,
    u16* __restrict__ Vc) {
  __shared__ __align__(16) char inb[98304];     // 3 input rows, [w][c-slot swizzled]
  char* scr = inb;                              // epilogue scratch (reused)
  int tid = threadIdx.x, lane = tid & 63, wv = tid >> 6;
  int b = blockIdx.x >> 7, h = blockIdx.x & 127;
  int m0 = (wv >> 1) * 64, n0 = (wv & 1) * 64;
  int laneoff = (lane & 15) * 256 + (lane >> 4) * 16;

  for (int r = 0; r < 3; ++r) {                 // stage 3 input rows (pre-swizzled in global)
    int hp = h + r - 1;
    if ((unsigned)hp >= 128u) continue;
    const char* src = (const char*)xnt + (size_t)(b * 128 + hp) * 32768;
    char* dst = inb + r * 32768;
#pragma unroll
    for (int i = 0; i < 8; ++i) {
      int off = i * 4096 + tid * 16;
      gload16(src + off, dst + off);
    }
  }
  __syncthreads();

  f32x4 aq[4][4] = {}, ak[4][4] = {}, av[4][4] = {};
  int4 bc[4][4];

  for (int tap = 0; tap < 9; ++tap) {
    int dy = tap / 3, dx = tap - dy * 3;
    int hp = h + dy - 1;
    if ((unsigned)hp >= 128u) continue;         // block-uniform
    const char* bt = inb + dy * 32768;
#pragma unroll
    for (int k0i = 0; k0i < 4; ++k0i)
#pragma unroll
      for (int ni = 0; ni < 4; ++ni) {
        int wp = n0 + ni * 16 + (lane & 15) + dx - 1;
        bool ok = (unsigned)wp < 128u;
        int wpc = ok ? wp : 0;
        int slot = (k0i * 4 + (lane >> 4)) ^ (wpc & 7);
        int4 v = *(const int4*)(bt + wpc * 256 + (slot << 4));
        if (!ok) v = make_int4(0, 0, 0, 0);
        bc[k0i][ni] = v;
      }
    const char* w0 = (const char*)weff + (size_t)(tap * 3) * 32768;
    CONV_COMPUTE2(aq, w0);
    CONV_COMPUTE2(ak, w0 + 32768);
    CONV_COMPUTE2(av, w0 + 65536);
  }
  __syncthreads();
  EPILOGUE(aq, Qc);
  EPILOGUE(ak, Kc);
  EPILOGUE(av, Vc);
}

// ---------------- K3: Gram via MFMA straight from global: attn[dk][dq] += sum_v K[v,dk]*Q[v,dq] ----
__global__ __launch_bounds__(256) void k_gram(const u16* __restrict__ Kc,
    const u16* __restrict__ Qc, float* __restrict__ attnb) {
  __shared__ float red[4][256];
  int tid = threadIdx.x, lane = tid & 63, wv = tid >> 6;
  int bhd = blockIdx.x >> 4, chunk = blockIdx.x & 15;   // 16 (b,hd) x 16 chunks of 1024 v
  size_t base = (size_t)bhd * 524288 + (size_t)chunk * 32768 + (size_t)wv * 8192
              + (lane >> 4) * 256 + (lane & 15) * 2;
  const char* kp = (const char*)Kc + base;
  const char* qp = (const char*)Qc + base;
  f32x4 acc = {};
  for (int s = 0; s < 8; ++s) {                 // 8 mfma x 32 v each = 256 v per wave
    PK a, q;
#pragma unroll
    for (int j = 0; j < 8; ++j) {
      a.u[j] = *(const u16*)(kp + s * 1024 + j * 32);
      q.u[j] = *(const u16*)(qp + s * 1024 + j * 32);
    }
    acc = mfma16(a.i, q.i, acc);
  }
#pragma unroll
  for (int r = 0; r < 4; ++r) red[wv][lane * 4 + r] = acc[r];
  __syncthreads();
  int cell = tid;                               // cell = lane*4 + r
  float s = red[0][cell] + red[1][cell] + red[2][cell] + red[3][cell];
  int l = cell >> 2, r = cell & 3;
  int dk = (l >> 4) * 4 + r, dq = l & 15;
  atomicAdd(&attnb[bhd * 256 + dk * 16 + dq], s);
}

// ---------------- K4: softmax + fold wo: W2[b][co][k=hd*16+dd] (f16, swizzled) --------------------
__global__ __launch_bounds__(256) void k_w2(const float* __restrict__ attnb,
    const void* __restrict__ wo, const void* __restrict__ scale,
    const int* __restrict__ flag, u16* __restrict__ w2s) {
  __shared__ float P[256];
  int b = blockIdx.x, hd = blockIdx.y;
  int tid = threadIdx.x;
  int isf = *flag;
  float sc = isf ? ((const float*)scale)[0] : b2f(((const u16*)scale)[0]);
  float inv_sc = 1.f / sc;
  P[tid] = attnb[(b * 8 + hd) * 256 + tid] * inv_sc;
  __syncthreads();
  if (tid < 16) {
    int dk = tid;
    float m = -1e30f;
#pragma unroll
    for (int j = 0; j < 16; ++j) m = fmaxf(m, P[dk * 16 + j]);
    float e[16]; float s = 0.f;
#pragma unroll
    for (int j = 0; j < 16; ++j) { e[j] = expf(P[dk * 16 + j] - m); s += e[j]; }
    float is = 1.f / s;
#pragma unroll
    for (int j = 0; j < 16; ++j) P[dk * 16 + j] = e[j] * is;
  }
  __syncthreads();
  int co = tid & 127, kg = tid >> 7;
  float wr[16];
  if (isf) {
    const float* wof = (const float*)wo;
#pragma unroll
    for (int d = 0; d < 16; ++d) wr[d] = wof[co * 128 + hd * 16 + d];
  } else {
    const u16* wou = (const u16*)wo;
#pragma unroll
    for (int d = 0; d < 16; ++d) wr[d] = b2f(wou[co * 128 + hd * 16 + d]);
  }
  PK p;
#pragma unroll
  for (int j = 0; j < 8; ++j) {
    int dd = kg * 8 + j;
    float a = 0.f;
#pragma unroll
    for (int d = 0; d < 16; ++d) a += wr[d] * P[dd * 16 + d];
    p.u[j] = f2h(a);
  }
  int slot = hd * 2 + kg;
  *(int4*)((char*)w2s + (size_t)b * 32768 + co * 256 + ((slot ^ (co & 7)) << 4)) = p.i;
}

// ---------------- K5: out = W2 @ Vbrick + x (per (b,h)) -------------------------------------------
__global__ __launch_bounds__(256, 1) void k_final(const u16* __restrict__ w2s,
    const u16* __restrict__ Vc, const void* __restrict__ xr,
    const int* __restrict__ flag, void* __restrict__ outr) {
  __shared__ __align__(16) char sW[32768];
  __shared__ __align__(16) char sBk[32768];
  int tid = threadIdx.x, lane = tid & 63, wv = tid >> 6;
  int b = blockIdx.x >> 7, h = blockIdx.x & 127;
  int isf = *flag;
  const char* wsrc = (const char*)w2s + (size_t)b * 32768;
#pragma unroll
  for (int i = 0; i < 8; ++i) {
    int off = i * 4096 + tid * 16;
    gload16(wsrc + off, sW + off);
  }
#pragma unroll
  for (int i = 0; i < 8; ++i) {                 // V brick: 128 gathered rows of Vc
    int gi = i * 256 + tid;
    int r = gi >> 4;
    int cv = (r >> 4) * 16 + (h >> 3);
    int hv = (h & 7) * 16 + (r & 15);
    const char* src = (const char*)Vc + (size_t)(b * 128 + cv) * 32768 + (size_t)hv * 256 + ((gi & 15) << 4);
    gload16(src, sBk + gi * 16);
  }
  __syncthreads();
  int m0 = (wv >> 1) * 64, n0 = (wv & 1) * 64;
  f32x4 acc[4][4] = {};
#pragma unroll
  for (int k0i = 0; k0i < 4; ++k0i) {
    int4 af[4], bfr[4];
#pragma unroll
    for (int mi = 0; mi < 4; ++mi) {
      int cc = m0 + mi * 16 + (lane & 15);
      int slot = (k0i * 4 + (lane >> 4)) ^ (cc & 7);
      af[mi] = *(const int4*)(sW + cc * 256 + (slot << 4));
    }
#pragma unroll
    for (int ni = 0; ni < 4; ++ni) {
      int w = n0 + ni * 16 + (lane & 15);
      int k = k0i * 32 + (lane >> 4) * 8;
      int hd8 = k >> 4, dd0 = k & 15;
      bfr[ni] = *(const int4*)(sBk + (hd8 * 16 + (w >> 3)) * 256 + ((w & 7) * 32 + dd0 * 2));
    }
#pragma unroll
    for (int mi = 0; mi < 4; ++mi)
#pragma unroll
      for (int ni = 0; ni < 4; ++ni)
        acc[mi][ni] = mfma16(af[mi], bfr[ni], acc[mi][ni]);
  }
  __syncthreads();
  if (isf) {
    const float* xf = (const float*)xr;
    float* of = (float*)outr;
#pragma unroll
    for (int mi = 0; mi < 4; ++mi)
#pragma unroll
      for (int ni = 0; ni < 4; ++ni) {
        int w = n0 + ni * 16 + (lane & 15);
#pragma unroll
        for (int r = 0; r < 4; ++r) {
          int cc = m0 + mi * 16 + (lane >> 4) * 4 + r;
          size_t idx = ((size_t)(b * 128 + cc) * 128 + (size_t)h) * 128 + w;
          of[idx] = acc[mi][ni][r] + xf[idx];
        }
      }
  } else {
    const u16* xu = (const u16*)xr;
#pragma unroll
    for (int mi = 0; mi < 4; ++mi)
#pragma unroll
      for (int ni = 0; ni < 4; ++ni) {
        int w = n0 + ni * 16 + (lane & 15);
#pragma unroll
        for (int r = 0; r < 4; ++r) {
          int cc = m0 + mi * 16 + (lane >> 4) * 4 + r;
          size_t idx = ((size_t)(b * 128 + cc) * 128 + (size_t)h) * 128 + w;
          *(u16*)(sW + cc * 256 + w * 2) = f2b(acc[mi][ni][r] + b2f(xu[idx]));
        }
      }
    __syncthreads();
    char* dstp = (char*)outr + (size_t)(b * 128) * 32768 + (size_t)h * 256;
#pragma unroll
    for (int i = 0; i < 8; ++i) {
      int sl = i * 256 + tid;
      int cc = sl >> 4;
      *(int4*)(dstp + (size_t)cc * 32768 + ((sl & 15) << 4)) = *(const int4*)(sW + sl * 16);
    }
  }
}

extern "C" void kernel_launch(void* const* d_in, const int* in_sizes, int n_in,
                              void* d_out, int out_size, void* d_ws, size_t ws_size,
                              hipStream_t stream) {
  (void)in_sizes; (void)n_in; (void)out_size; (void)ws_size;
  const void* x     = d_in[0];
  const void* gamma = d_in[1];
  const void* beta  = d_in[2];
  const void* scale = d_in[3];
  const void* w1q = d_in[4];
  const void* w2q = d_in[5];
  const void* w1k = d_in[6];
  const void* w2k = d_in[7];
  const void* w1v = d_in[8];
  const void* w2v = d_in[9];
  const void* wo  = d_in[10];
  char* ws = (char*)d_ws;
  u16* xnt     = (u16*)(ws);                           // 8 MB  [b][h][w][c] f16 swizzled
  u16* weff    = (u16*)(ws + (8u << 20));              // 864 KB fused 3x3 weights f16, LINEAR
  u16* Qc      = (u16*)(ws + (9u << 20));              // 8 MB each, [b][c][h][w] f16
  u16* Kc      = (u16*)(ws + (17u << 20));
  u16* Vc      = (u16*)(ws + (25u << 20));
  float* attnb = (float*)(ws + (33u << 20));           // 16 KB f32
  u16* w2s     = (u16*)(ws + (33u << 20) + 65536);     // 64 KB f16, swizzled
  int* flag    = (int*)(ws + (33u << 20) + 196608);

  hipMemsetAsync(attnb, 0, 2 * 8 * 16 * 16 * sizeof(float), stream);
  hipLaunchKernelGGL(k_detect, dim3(1), dim3(256), 0, stream, (const u16*)x, flag);
  hipLaunchKernelGGL(k_weff, dim3(27), dim3(256), 0, stream, w1q, w2q, w1k, w2k, w1v, w2v, flag, weff);
  hipLaunchKernelGGL(k_ln, dim3(256), dim3(256), 0, stream, x, gamma, beta, flag, xnt);
  hipLaunchKernelGGL(k_conv, dim3(256), dim3(256), 0, stream, xnt, weff, Qc, Kc, Vc);
  hipLaunchKernelGGL(k_gram, dim3(256), dim3(256), 0, stream, Kc, Qc, attnb);
  hipLaunchKernelGGL(k_w2, dim3(2, 8), dim3(256), 0, stream, attnb, wo, scale, flag, w2s);
  hipLaunchKernelGGL(k_final, dim3(256), dim3(256), 0, stream, w2s, Vc, x, flag, d_out);
}